// Round 8
// baseline (302.932 us; speedup 1.0000x reference)
//
#include <hip/hip_runtime.h>
#include <hip/hip_bf16.h>

#define NROWS 131072
#define KEXP 16
#define MPC 128
#define DIMD 64

typedef float f32x16 __attribute__((ext_vector_type(16)));
typedef short s16x8  __attribute__((ext_vector_type(8)));

#define L2E 1.4426950408889634f
#define LN2 0.6931471805599453f

static __device__ inline unsigned int b2u(__hip_bfloat162 h) {
    union { __hip_bfloat162 h; unsigned int u; } c;
    c.h = h;
    return c.u;
}

static __device__ inline int4 cvt8s(float4 f0, float4 f1, float sc) {
    __hip_bfloat162 p0 = __float22bfloat162_rn(make_float2(f0.x * sc, f0.y * sc));
    __hip_bfloat162 p1 = __float22bfloat162_rn(make_float2(f0.z * sc, f0.w * sc));
    __hip_bfloat162 p2 = __float22bfloat162_rn(make_float2(f1.x * sc, f1.y * sc));
    __hip_bfloat162 p3 = __float22bfloat162_rn(make_float2(f1.z * sc, f1.w * sc));
    int4 pk;
    pk.x = (int)b2u(p0); pk.y = (int)b2u(p1); pk.z = (int)b2u(p2); pk.w = (int)b2u(p3);
    return pk;
}

// Round-8: MONOLITHIC zero-prep kernel.
// Evidence: (1) total-minus-fused is a constant ~64us across ALL rounds
// (prep dispatch + serialization + overhead) — as large as fused itself.
// (2) Four fused structures all land 55-57us with every pipe <=50% busy and
// occupancy pinned at 4 waves/SIMD (<=64-reg regime unreachable: R3/R5/R7 all
// spilled). So attack the dispatch structure instead.
// Design: ONE kernel, grid 1024 x 256. Each block owns 128 rows (wave w: 32
// rows) and loops over ALL 16 experts. A (512 KB f32, L2-resident) is read
// DIRECTLY from global per fragment (8 dwordx4 + 1 bias dword per (k,mt)) and
// converted to bf16 in-register — the exact fragment mapping prep used to
// prepack, so the math is bit-identical to the verified R0/R4 kernels.
// Removes: prep kernel, workspace, all DMA, ALL barriers, all LDS, atomics,
// out-zeroing (each row plain-stored exactly once -> idempotent across reps).
// MFMA 32x32x16, bias as 5th MFMA with constant-B ones (verified R0 trick).
// Spill canary: WRITE_SIZE ~1 MB; VGPR expected ~80-100 (4 waves/SIMD honest).
__global__ __launch_bounds__(256, 4)
void fused_kernel(const float* __restrict__ x, const float* __restrict__ s,
                  const float* __restrict__ a, const float* __restrict__ b,
                  float* __restrict__ out) {
    const int tid  = threadIdx.x;
    const int w    = tid >> 6;
    const int l    = tid & 63;
    const int ln   = l & 31;
    const int half = l >> 5;

    const int r0 = blockIdx.x * 128 + w * 32;   // wave owns rows r0 .. r0+31

    // persistent x B-fragments: Bf[c] = x[r0 + ln][c*16 + half*8 ..+7]
    union { int4 i; s16x8 v; } Bf[4];
#pragma unroll
    for (int c = 0; c < 4; ++c) {
        const float* gp = x + (size_t)(r0 + ln) * DIMD + c * 16 + half * 8;
        float4 f0 = *(const float4*)(gp);
        float4 f1 = *(const float4*)(gp + 4);
        Bf[c].i = cvt8s(f0, f1, 1.0f);
    }

    // constant bias-B: B[n][k'=0] = 1.0 (k'=0 lives on half==0 lanes, element 0)
    union { int4 i; s16x8 v; } Bones;
    Bones.i.x = (half == 0) ? 0x3F80 : 0;   // bf16(1.0) in element 0
    Bones.i.y = 0; Bones.i.z = 0; Bones.i.w = 0;

    float racc = 0.f;

    for (int k = 0; k < KEXP; ++k) {
        const float* aK = a + (size_t)k * MPC * DIMD;
        const float* bK = b + k * MPC;
        const float sk2 = s[k] * LN2;

        float s0 = 0.f, s1 = 0.f, s2 = 0.f, s3 = 0.f;

        for (int mt = 0; mt < 4; ++mt) {
            // A-fragment row base for this lane: a[k][mt*32 + ln][half*8 ...]
            const float* ap = aK + (size_t)(mt * 32 + ln) * DIMD + half * 8;

            f32x16 acc = {};
#pragma unroll
            for (int c = 0; c < 4; ++c) {
                union { int4 i; s16x8 v; } Af;
                float4 f0 = *(const float4*)(ap + c * 16);
                float4 f1 = *(const float4*)(ap + c * 16 + 4);
                Af.i = cvt8s(f0, f1, L2E);
                acc = __builtin_amdgcn_mfma_f32_32x32x16_bf16(Af.v, Bf[c].v, acc, 0, 0, 0);
            }
            // bias as 5th MFMA: A[m][k'=0] = b[k][mt*32+m]*L2E on half==0, elem 0
            {
                union { int4 i; s16x8 v; } Ab;
                union { __hip_bfloat16 h; unsigned short us; } cb;
                cb.h = __float2bfloat16(bK[mt * 32 + ln] * L2E);
                Ab.i.x = (half == 0) ? (int)cb.us : 0;
                Ab.i.y = 0; Ab.i.z = 0; Ab.i.w = 0;
                acc = __builtin_amdgcn_mfma_f32_32x32x16_bf16(Ab.v, Bones.v, acc, 0, 0, 0);
            }
            // softmax partial sums: 16 score elements per lane (4 indep chains)
#pragma unroll
            for (int r = 0; r < 4; ++r) {
                s0 += __builtin_amdgcn_exp2f(acc[4 * r + 0]);
                s1 += __builtin_amdgcn_exp2f(acc[4 * r + 1]);
                s2 += __builtin_amdgcn_exp2f(acc[4 * r + 2]);
                s3 += __builtin_amdgcn_exp2f(acc[4 * r + 3]);
            }
        }

        // combine m-halves (lanes l and l^32 cover the other 16 m-rows)
        float tot = (s0 + s1) + (s2 + s3);
        tot += __shfl_xor(tot, 32);
        racc = fmaf(sk2, __log2f(tot), racc);
    }

    // each row written exactly once by one lane: no atomics, no pre-zero needed
    if (half == 0)
        out[r0 + ln] = racc;
}

extern "C" void kernel_launch(void* const* d_in, const int* in_sizes, int n_in,
                              void* d_out, int out_size, void* d_ws, size_t ws_size,
                              hipStream_t stream) {
    const float* x = (const float*)d_in[0];
    const float* s = (const float*)d_in[1];
    const float* a = (const float*)d_in[2];
    const float* b = (const float*)d_in[3];
    float* out = (float*)d_out;

    fused_kernel<<<NROWS / 128, 256, 0, stream>>>(x, s, a, b, out);
}

// Round 9
// 120.117 us; speedup vs baseline: 2.5220x; 2.5220x over previous
//
#include <hip/hip_runtime.h>
#include <hip/hip_bf16.h>

#define NROWS 131072
#define KEXP 16
#define MPC 128
#define DIMD 64

typedef float f32x16 __attribute__((ext_vector_type(16)));
typedef short s16x8  __attribute__((ext_vector_type(8)));

#define L2E 1.4426950408889634f
#define LN2 0.6931471805599453f

static __device__ inline unsigned int b2u(__hip_bfloat162 h) {
    union { __hip_bfloat162 h; unsigned int u; } c;
    c.h = h;
    return c.u;
}

static __device__ inline int4 cvt8s(float4 f0, float4 f1, float sc) {
    __hip_bfloat162 p0 = __float22bfloat162_rn(make_float2(f0.x * sc, f0.y * sc));
    __hip_bfloat162 p1 = __float22bfloat162_rn(make_float2(f0.z * sc, f0.w * sc));
    __hip_bfloat162 p2 = __float22bfloat162_rn(make_float2(f1.x * sc, f1.y * sc));
    __hip_bfloat162 p3 = __float22bfloat162_rn(make_float2(f1.z * sc, f1.w * sc));
    int4 pk;
    pk.x = (int)b2u(p0); pk.y = (int)b2u(p1); pk.z = (int)b2u(p2); pk.w = (int)b2u(p3);
    return pk;
}

// async 16B/lane global->LDS DMA (wave-uniform LDS base + lane*16)
static __device__ inline void async_copy16(const void* g, void* l) {
    __builtin_amdgcn_global_load_lds(
        (const __attribute__((address_space(1))) unsigned int*)g,
        (__attribute__((address_space(3))) unsigned int*)l, 16, 0, 0);
}

// abff: A-only pack. Per expert k: 16 chunks c2 = mt*4+c (1 KB each, 16 KB/expert).
// Lane ul of chunk (k,mt,c): 8 bf16 = a[k][mt*32 + (ul&31)][c*16 + (ul>>5)*8 + j]*L2E
// (identical fragment bytes to the verified R0/R4 layout, bias chunks dropped).
__global__ void prep_kernel(const float* __restrict__ a, short* __restrict__ abff) {
    const int u  = blockIdx.x * 256 + threadIdx.x;   // 0..16383
    const int k  = u >> 10;
    const int c2 = (u >> 6) & 15;
    const int ul = u & 63;
    const int mt = c2 >> 2;
    const int c  = c2 & 3;
    const float* p = a + (size_t)(k * MPC + mt * 32 + (ul & 31)) * DIMD
                       + c * 16 + (ul >> 5) * 8;
    int4 pk = cvt8s(*(const float4*)(p), *(const float4*)(p + 4), L2E);
    *(int4*)(abff + (size_t)u * 8) = pk;
}

// Round-9: ZERO-steady-state-barrier design.
// Evidence: R0/R4/R6 all 55-57us with every pipe <=50%; 8-wave/SIMD regime
// unreachable (R3/R5/R7 spills); ILP null (R6); direct global A reads fatal
// (R8, latency). The one untested shared feature of all 55us variants: 16
// barrier+vmcnt(0) convergence points. This kernel stages 8 experts (128 KB
// bf16) in LDS at once: block = 1024 thr (16 waves) x grid 256 = exactly
// 1 block/CU, no tail. Compute phase has NO barriers (LDS read-only); one
// barrier pair mid-kernel swaps in experts 8-15. 3 barriers total vs 16.
// Bias via 4 coalesced L1 dword loads per expert + in-register bf16 construct
// (the R8-verified path). Inner fragment math identical to verified R0/R4.
// Each row stored exactly once (no atomics, no pre-zero, no out-zero in prep).
// Spill canary: WRITE_SIZE ~1 MB.
__global__ __launch_bounds__(1024, 4)
void fused_kernel(const float* __restrict__ x, const float* __restrict__ s,
                  const short* __restrict__ abff, const float* __restrict__ b,
                  float* __restrict__ out) {
    __shared__ int4 Albs[8192];   // 128 KB: chunk ci at byte ci*1024

    const int tid  = threadIdx.x;
    const int wv   = tid >> 6;    // 0..15
    const int l    = tid & 63;
    const int ln   = l & 31;
    const int half = l >> 5;

    const int r0 = blockIdx.x * 512 + wv * 32;   // wave owns rows r0..r0+31

    const char* ab = (const char*)abff;

    // ---- issue phase-0 DMA first (fire-and-forget), then x loads overlap it
#pragma unroll
    for (int i = 0; i < 8; ++i) {
        const int ci = wv * 8 + i;                 // 128 chunks = experts 0..7
        async_copy16(ab + (size_t)ci * 1024 + l * 16, (char*)Albs + ci * 1024);
    }

    // persistent x B-fragments: Bf[c] = x[r0 + ln][c*16 + half*8 ..+7]
    union { int4 i; s16x8 v; } Bf[4];
    {
        float4 f[8];
#pragma unroll
        for (int c = 0; c < 4; ++c) {
            const float* gp = x + (size_t)(r0 + ln) * DIMD + c * 16 + half * 8;
            f[2 * c]     = *(const float4*)(gp);
            f[2 * c + 1] = *(const float4*)(gp + 4);
        }
#pragma unroll
        for (int c = 0; c < 4; ++c)
            Bf[c].i = cvt8s(f[2 * c], f[2 * c + 1], 1.0f);
    }

    // constant bias-B: B[n][k'=0] = 1.0 (k'=0 lives on half==0 lanes, element 0)
    union { int4 i; s16x8 v; } Bones;
    Bones.i.x = (half == 0) ? 0x3F80 : 0;   // bf16(1.0) in element 0
    Bones.i.y = 0; Bones.i.z = 0; Bones.i.w = 0;

    __syncthreads();   // drains DMA (vmcnt0 before s_barrier); phase-0 LDS ready

    float racc = 0.f;

#define COMPUTE_PHASE(P)                                                            \
    for (int kl = 0; kl < 8; ++kl) {                                                \
        const int kf = (P) * 8 + kl;                                                \
        /* bias loads issued early (L1-resident, 128B coalesced each) */            \
        float bias_mt[4];                                                           \
        _Pragma("unroll")                                                           \
        for (int mt = 0; mt < 4; ++mt)                                              \
            bias_mt[mt] = b[kf * MPC + mt * 32 + ln];                               \
        const float sk2 = s[kf] * LN2;                                              \
        float s0 = 0.f, s1 = 0.f, s2 = 0.f, s3 = 0.f;                               \
        for (int mt = 0; mt < 4; ++mt) {                                            \
            const char* base = (const char*)Albs + (kl * 16 + mt * 4) * 1024 + l * 16; \
            f32x16 acc = {};                                                        \
            _Pragma("unroll")                                                       \
            for (int c = 0; c < 4; ++c) {                                           \
                s16x8 Af = *(const s16x8*)(base + c * 1024);                        \
                acc = __builtin_amdgcn_mfma_f32_32x32x16_bf16(Af, Bf[c].v, acc, 0, 0, 0); \
            }                                                                       \
            {                                                                       \
                union { int4 i; s16x8 v; } Ab;                                      \
                union { __hip_bfloat16 h; unsigned short us; } cb;                  \
                cb.h = __float2bfloat16(bias_mt[mt] * L2E);                         \
                Ab.i.x = (half == 0) ? (int)cb.us : 0;                              \
                Ab.i.y = 0; Ab.i.z = 0; Ab.i.w = 0;                                 \
                acc = __builtin_amdgcn_mfma_f32_32x32x16_bf16(Ab.v, Bones.v, acc, 0, 0, 0); \
            }                                                                       \
            _Pragma("unroll")                                                       \
            for (int r = 0; r < 4; ++r) {                                           \
                s0 += __builtin_amdgcn_exp2f(acc[4 * r + 0]);                       \
                s1 += __builtin_amdgcn_exp2f(acc[4 * r + 1]);                       \
                s2 += __builtin_amdgcn_exp2f(acc[4 * r + 2]);                       \
                s3 += __builtin_amdgcn_exp2f(acc[4 * r + 3]);                       \
            }                                                                       \
        }                                                                           \
        float tot = (s0 + s1) + (s2 + s3);                                          \
        tot += __shfl_xor(tot, 32);                                                 \
        racc = fmaf(sk2, __log2f(tot), racc);                                       \
    }

    // -------- phase 0: experts 0..7, ZERO barriers --------
    COMPUTE_PHASE(0)

    __syncthreads();   // all waves done reading phase-0 LDS

    // DMA experts 8..15 into the same LDS
#pragma unroll
    for (int i = 0; i < 8; ++i) {
        const int ci = wv * 8 + i;
        async_copy16(ab + 131072 + (size_t)ci * 1024 + l * 16, (char*)Albs + ci * 1024);
    }
    __syncthreads();   // drain DMA; phase-1 LDS ready

    // -------- phase 1: experts 8..15, ZERO barriers --------
    COMPUTE_PHASE(1)
#undef COMPUTE_PHASE

    // each row written exactly once by one lane: no atomics, no pre-zero needed
    if (half == 0)
        out[r0 + ln] = racc;
}

extern "C" void kernel_launch(void* const* d_in, const int* in_sizes, int n_in,
                              void* d_out, int out_size, void* d_ws, size_t ws_size,
                              hipStream_t stream) {
    const float* x = (const float*)d_in[0];
    const float* s = (const float*)d_in[1];
    const float* a = (const float*)d_in[2];
    const float* b = (const float*)d_in[3];
    float* out = (float*)d_out;

    short* abff = (short*)d_ws;   // 16 experts x 16 KB = 256 KB

    prep_kernel<<<64, 256, 0, stream>>>(a, abff);
    fused_kernel<<<NROWS / 512, 1024, 0, stream>>>(x, s, abff, b, out);
}